// Round 8
// baseline (124.216 us; speedup 1.0000x reference)
//
#include <hip/hip_runtime.h>
#include <hip/hip_bf16.h>
#include <cstddef>

// Problem constants
#define DIMC   128
#define NHEADS 8
#define HDIM   16
#define DD     5
#define HH     24
#define WW_    48
#define NPOS   (DD * HH * WW_)     // 5760
#define SCALE  0.25f

typedef short  bf16x8 __attribute__((ext_vector_type(8)));
typedef float  f32x4  __attribute__((ext_vector_type(4)));

__device__ __forceinline__ unsigned short f2bf(float f) {
    unsigned u = __float_as_uint(f);
    u = (u + 0x7FFFu + ((u >> 16) & 1u)) >> 16;   // RNE
    return (unsigned short)u;
}
__device__ __forceinline__ float bf2f(unsigned short s) {
    return __uint_as_float(((unsigned)s) << 16);
}

// ---------------------------------------------------------------------------
// prep: fp32 -> bf16 3-term split expansion.
//   A-side (x):       [hi(128) | lo(128) | hi(128)]
//   B-side (weights): [hi(128) | hi(128) | lo(128)]
// Pairing: hi*hi + lo*hi + hi*lo == full product minus negligible lo*lo.
// ---------------------------------------------------------------------------
__global__ __launch_bounds__(256) void prep_kernel(
    const float* __restrict__ x,
    const float* __restrict__ wq,
    const float* __restrict__ wp,
    unsigned short* __restrict__ Axq,
    unsigned short* __restrict__ Bxq,
    unsigned short* __restrict__ Bxp)
{
    const int i = blockIdx.x * 256 + threadIdx.x;   // one float4 each
    const bool isA = (i < 184320);
    const float* src; unsigned short* dst; int rel;
    if (isA)             { src = x;  dst = Axq; rel = i; }
    else if (i < 196608) { src = wq; dst = Bxq; rel = i - 184320; }
    else                 { src = wp; dst = Bxp; rel = i - 196608; }
    const int row = rel >> 5;
    const int c4  = rel & 31;
    const float4 v = *(const float4*)(src + (size_t)row * 128 + c4 * 4);
    ushort4 hi, lo;
    hi.x = f2bf(v.x); hi.y = f2bf(v.y); hi.z = f2bf(v.z); hi.w = f2bf(v.w);
    lo.x = f2bf(v.x - bf2f(hi.x));
    lo.y = f2bf(v.y - bf2f(hi.y));
    lo.z = f2bf(v.z - bf2f(hi.z));
    lo.w = f2bf(v.w - bf2f(hi.w));
    unsigned short* p = dst + (size_t)row * 384 + c4 * 4;
    if (isA) {
        *(ushort4*)(p)       = hi;
        *(ushort4*)(p + 128) = lo;
        *(ushort4*)(p + 256) = hi;
    } else {
        *(ushort4*)(p)       = hi;
        *(ushort4*)(p + 128) = hi;
        *(ushort4*)(p + 256) = lo;
    }
}

// ---------------------------------------------------------------------------
// LDS-free streaming MFMA GEMM: C[M][N] = A'[M][384] @ B'[N][384]^T + bias.
// No LDS, no barriers: each wave computes a 16(M)x64(N) strip, A/B fragments
// loaded straight from global (B' is L2-resident: 0.3 MB re-read ~90x ≈
// 100 MB of L2 traffic ≈ 3 µs @ 34 TB/s). Block 256 = 4 independent waves
// stacked in M. EPI 0: fp32 C. EPI 1 (QKV): Q fp32 coalesced, K/V bf16.
// ---------------------------------------------------------------------------
template <int EPI>
__global__ __launch_bounds__(256, 4) void gemm_stream_kernel(
    const unsigned short* __restrict__ Ax,
    const unsigned short* __restrict__ Bx,
    const float* __restrict__ bias,
    float* __restrict__ C, int ldc,
    float* __restrict__ Qf32,
    unsigned short* __restrict__ Kbf,
    unsigned short* __restrict__ Vbf)
{
    const int tid  = threadIdx.x;
    const int w    = tid >> 6;
    const int lane = tid & 63;
    const int ln   = lane & 15;
    const int quad = lane >> 4;
    const int bn   = blockIdx.x * 64;
    const int bm   = blockIdx.y * 64;

    const unsigned short* aptr = Ax + (size_t)(bm + w * 16 + ln) * 384 + quad * 8;
    const unsigned short* bptr0 = Bx + (size_t)(bn + ln) * 384 + quad * 8;
    const unsigned short* bptr1 = bptr0 + (size_t)16 * 384;
    const unsigned short* bptr2 = bptr0 + (size_t)32 * 384;
    const unsigned short* bptr3 = bptr0 + (size_t)48 * 384;

    f32x4 acc[4] = {};
    #pragma unroll
    for (int kc = 0; kc < 12; ++kc) {
        const bf16x8 a  = *(const bf16x8*)(aptr  + kc * 32);
        const bf16x8 b0 = *(const bf16x8*)(bptr0 + kc * 32);
        const bf16x8 b1 = *(const bf16x8*)(bptr1 + kc * 32);
        const bf16x8 b2 = *(const bf16x8*)(bptr2 + kc * 32);
        const bf16x8 b3 = *(const bf16x8*)(bptr3 + kc * 32);
        acc[0] = __builtin_amdgcn_mfma_f32_16x16x32_bf16(a, b0, acc[0], 0, 0, 0);
        acc[1] = __builtin_amdgcn_mfma_f32_16x16x32_bf16(a, b1, acc[1], 0, 0, 0);
        acc[2] = __builtin_amdgcn_mfma_f32_16x16x32_bf16(a, b2, acc[2], 0, 0, 0);
        acc[3] = __builtin_amdgcn_mfma_f32_16x16x32_bf16(a, b3, acc[3], 0, 0, 0);
    }

    #pragma unroll
    for (int nt = 0; nt < 4; ++nt) {
        const int col = bn + nt * 16 + ln;
        const float bv = bias[col];
        #pragma unroll
        for (int r = 0; r < 4; ++r) {
            const int row = bm + w * 16 + quad * 4 + r;
            const float val = acc[nt][r] + bv;
            if (EPI == 0) {
                C[(size_t)row * ldc + col] = val;
            } else {
                if (col < 128) {               // q -> fp32, coalesced dwords
                    Qf32[(size_t)row * 128 + col] = val;
                } else if (col < 256) {        // k -> bf16
                    Kbf[(size_t)row * 128 + (col - 128)] = f2bf(val);
                } else {                       // v -> bf16
                    Vbf[(size_t)row * 128 + (col - 256)] = f2bf(val);
                }
            }
        }
    }
}

// ---------------------------------------------------------------------------
// Fused neighborhood attention, split-chunk version.
// Grid (72 tiles of 4x4, 8 heads), 640 threads = 10 waves. Wave w handles
// depth slab (w%5) and chunk-half (w/5): 8 serial chunks instead of 16 —
// halves the per-wave latency chain (score MFMA -> exp -> P LDS round-trip
// -> PV MFMA) and doubles wave parallelism (5760 waves = 5.6/SIMD).
// Halves combine via a small LDS O/l reduction (2 extra barriers).
// ---------------------------------------------------------------------------
__global__ __launch_bounds__(640, 5) void attn_kernel(
    const float* __restrict__ Qf32,           // [5760][128] fp32 q
    const unsigned short* __restrict__ Kbf,   // [5760][128] bf16
    const unsigned short* __restrict__ Vbf,   // [5760][128] bf16
    unsigned short* __restrict__ Ap)          // [5760][384] bf16 hi|lo|hi
{
    __shared__ __align__(16) unsigned short Vt[16][520];        // 16640 B  V^T
    __shared__ __align__(16) unsigned short Qb[80][40];         //  6400 B  [hi16|lo16|pad]
    __shared__ __align__(16) unsigned short Pw[10][2][16][40];  // 25600 B  per-wave P
    __shared__ unsigned short Mb2[16][34];                      //  1088 B  mask bits
    __shared__ int RowL[512];                                   //  2048 B  u -> row
    // overlay (after barrier): redO[10][16ch][16m] f32 (10240 B) on Vt
    float* redO  = (float*)&Vt[0][0];
    __shared__ float red_l[10][16];

    const int tile = blockIdx.x;
    const int h    = blockIdx.y;
    const int ty0  = (tile / 12) * 4;
    const int tx0  = (tile % 12) * 4;
    const int tid  = threadIdx.x;

    // ---- RowL LUT: u -> wrapped global position (clamped for u>=500) ----
    for (int u = tid; u < 512; u += 640) {
        const int uc = u < 500 ? u : 499;
        const int dp = uc / 100, rr = uc % 100;
        const int uy = rr / 10,  ux = rr % 10;
        int y = ty0 - 3 + uy; if (y < 0) y += HH;  if (y >= HH) y -= HH;
        int x = tx0 - 3 + ux; if (x < 0) x += WW_; if (x >= WW_) x -= WW_;
        RowL[u] = (dp * HH + y) * WW_ + x;
    }
    // ---- mask LUT: Mb2[ln][t] bit b = (u=16t+b valid for query ln) ----
    for (int i = tid; i < 512; i += 640) {
        const int t = i >> 4, ql = i & 15;
        const int sy = ql >> 2, sx = ql & 3;
        unsigned bits = 0;
        #pragma unroll
        for (int b = 0; b < 16; ++b) {
            const int u = t * 16 + b;
            const int rr = u % 100;
            const int uy = rr / 10, ux = rr % 10;
            if (u < 500 && (unsigned)(uy - sy) <= 6u && (unsigned)(ux - sx) <= 6u)
                bits |= 1u << b;
        }
        Mb2[ql][t] = (unsigned short)bits;
    }
    // ---- stage V^T: item = u-pair, dword-packed writes ----
    for (int i = tid; i < 256; i += 640) {
        const int u0 = i * 2;
        unsigned short va[16], vb[16];
        #pragma unroll
        for (int c = 0; c < 16; ++c) { va[c] = 0; vb[c] = 0; }
        #pragma unroll
        for (int half = 0; half < 2; ++half) {
            const int u = u0 + half;
            if (u < 500) {
                const int dp = u / 100, rr = u % 100;
                const int uy = rr / 10,  ux = rr % 10;
                int y = ty0 - 3 + uy; if (y < 0) y += HH;  if (y >= HH) y -= HH;
                int x = tx0 - 3 + ux; if (x < 0) x += WW_; if (x >= WW_) x -= WW_;
                const int g = (dp * HH + y) * WW_ + x;
                const bf16x8 p0 = *(const bf16x8*)(Vbf + (size_t)g * 128 + h * 16);
                const bf16x8 p1 = *(const bf16x8*)(Vbf + (size_t)g * 128 + h * 16 + 8);
                unsigned short* dst = half ? vb : va;
                #pragma unroll
                for (int c = 0; c < 8; ++c) { dst[c] = (unsigned short)p0[c]; dst[8 + c] = (unsigned short)p1[c]; }
            }
        }
        #pragma unroll
        for (int c = 0; c < 16; ++c)
            *(unsigned*)(&Vt[c][u0]) = (unsigned)va[c] | ((unsigned)vb[c] << 16);
    }
    // ---- stage Q tile: fp32 read, hi/lo split here (one-time) ----
    for (int i = tid; i < 1280; i += 640) {
        const int p = i >> 4, c = i & 15;
        const int d = p >> 4, s = p & 15;
        const int sy = s >> 2, sx = s & 3;
        const int g = (d * HH + ty0 + sy) * WW_ + tx0 + sx;
        const float qv = Qf32[(size_t)g * 128 + h * 16 + c];
        const unsigned short hi = f2bf(qv);
        Qb[p][c]      = hi;
        Qb[p][16 + c] = f2bf(qv - bf2f(hi));
    }
    __syncthreads();

    const int w     = tid >> 6;    // 0..9
    const int wslab = w % 5;       // depth slab
    const int c0    = (w / 5) * 8; // chunk half: chunks c0..c0+7
    const int lane  = tid & 63;
    const int ln    = lane & 15;
    const int quad  = lane >> 4;

    const bf16x8 qf = *(const bf16x8*)(&Qb[wslab * 16 + ln][quad * 8]);
    f32x4 Ow = {0.f, 0.f, 0.f, 0.f};
    float lsum = 0.f;

    const float C1 = SCALE * 1.44269504f;   // log2(e)*scale
    const float C0 = -11.5415603f;          // -8*log2(e) (shift cancels in softmax)

    const int koff = h * 16 + (quad & 1) * 8;
    bf16x8 k0 = *(const bf16x8*)(Kbf + (size_t)RowL[c0 * 32 + ln]      * 128 + koff);
    bf16x8 k1 = *(const bf16x8*)(Kbf + (size_t)RowL[c0 * 32 + 16 + ln] * 128 + koff);

    #pragma unroll 2
    for (int c = c0; c < c0 + 8; ++c) {
        const int u0 = c * 32;
        bf16x8 n0 = k0, n1 = k1;
        if (c < c0 + 7) {
            n0 = *(const bf16x8*)(Kbf + (size_t)RowL[u0 + 32 + ln] * 128 + koff);
            n1 = *(const bf16x8*)(Kbf + (size_t)RowL[u0 + 48 + ln] * 128 + koff);
        }
        const unsigned mb = *(const unsigned*)(&Mb2[ln][2 * c]);   // tiles 2c|2c+1
        const unsigned m0 = (mb >> (quad * 4)) & 0xF;
        const unsigned m1 = (mb >> (16 + quad * 4)) & 0xF;

        f32x4 s0 = __builtin_amdgcn_mfma_f32_16x16x32_bf16(k0, qf, (f32x4){0.f,0.f,0.f,0.f}, 0, 0, 0);
        f32x4 s1 = __builtin_amdgcn_mfma_f32_16x16x32_bf16(k1, qf, (f32x4){0.f,0.f,0.f,0.f}, 0, 0, 0);

        unsigned short* pw = &Pw[w][c & 1][ln][0];
        #pragma unroll
        for (int t = 0; t < 2; ++t) {
            const f32x4 s = t ? s1 : s0;
            const unsigned m = t ? m1 : m0;
            unsigned eu[4];
            #pragma unroll
            for (int r = 0; r < 4; ++r) {
                const float arg = ((m >> r) & 1u) ? fmaf(s[r], C1, C0) : -100.f;
                const unsigned trunc = __float_as_uint(exp2f(arg)) & 0xFFFF0000u;
                eu[r] = trunc;
                lsum += __uint_as_float(trunc);
            }
            unsigned* dst = (unsigned*)(pw + t * 16 + quad * 4);
            dst[0] = (eu[0] >> 16) | eu[1];
            dst[1] = (eu[2] >> 16) | eu[3];
        }

        const bf16x8 vf = *(const bf16x8*)(&Vt[ln][u0 + quad * 8]);
        const bf16x8 pf = *(const bf16x8*)(&Pw[w][c & 1][ln][quad * 8]);
        Ow = __builtin_amdgcn_mfma_f32_16x16x32_bf16(vf, pf, Ow, 0, 0, 0);

        k0 = n0; k1 = n1;
    }

    // ---- l: reduce across quads within wave ----
    lsum += __shfl_xor(lsum, 16);
    lsum += __shfl_xor(lsum, 32);

    __syncthreads();   // all Vt/Qb/Pw reads done; safe to overlay redO

    if (quad == 0) red_l[w][ln] = lsum;
    #pragma unroll
    for (int r = 0; r < 4; ++r)
        redO[(size_t)(w * 16 + quad * 4 + r) * 16 + ln] = Ow[r];
    __syncthreads();

    // ---- waves 0..4 combine the two halves, normalize, write Ap ----
    if (tid < 320) {
        const float l = red_l[w][ln] + red_l[w + 5][ln];
        const float inv = 1.0f / l;
        f32x4 o;
        #pragma unroll
        for (int r = 0; r < 4; ++r)
            o[r] = redO[(size_t)(w * 16 + quad * 4 + r) * 16 + ln]
                 + redO[(size_t)((w + 5) * 16 + quad * 4 + r) * 16 + ln];

        const int sy = ln >> 2, sx = ln & 3;
        const size_t g = (size_t)((w * HH + ty0 + sy) * WW_ + (tx0 + sx));
        ushort4 hi4, lo4;
        {
            float v0 = o[0] * inv, v1 = o[1] * inv, v2 = o[2] * inv, v3 = o[3] * inv;
            hi4.x = f2bf(v0); lo4.x = f2bf(v0 - bf2f(hi4.x));
            hi4.y = f2bf(v1); lo4.y = f2bf(v1 - bf2f(hi4.y));
            hi4.z = f2bf(v2); lo4.z = f2bf(v2 - bf2f(hi4.z));
            hi4.w = f2bf(v3); lo4.w = f2bf(v3 - bf2f(hi4.w));
        }
        unsigned short* row = Ap + g * 384 + h * HDIM + quad * 4;
        *(ushort4*)(row)       = hi4;
        *(ushort4*)(row + 128) = lo4;
        *(ushort4*)(row + 256) = hi4;
    }
}

// ---------------------------------------------------------------------------
extern "C" void kernel_launch(void* const* d_in, const int* in_sizes, int n_in,
                              void* d_out, int out_size, void* d_ws, size_t ws_size,
                              hipStream_t stream)
{
    const float* x      = (const float*)d_in[0];
    const float* qkv_w  = (const float*)d_in[1];
    const float* qkv_b  = (const float*)d_in[2];
    const float* proj_w = (const float*)d_in[3];
    const float* proj_b = (const float*)d_in[4];
    float* out = (float*)d_out;

    char* ws = (char*)d_ws;
    unsigned short* Axq = (unsigned short*)ws;  ws += (size_t)NPOS * 384 * 2;  // x  hi|lo|hi
    unsigned short* Ap  = (unsigned short*)ws;  ws += (size_t)NPOS * 384 * 2;  // attn out hi|lo|hi
    unsigned short* Bxq = (unsigned short*)ws;  ws += (size_t)384 * 384 * 2;
    unsigned short* Bxp = (unsigned short*)ws;  ws += (size_t)128 * 384 * 2;
    float*          Qf  = (float*)ws;           ws += (size_t)NPOS * 128 * 4;  // q fp32
    unsigned short* Kbf = (unsigned short*)ws;  ws += (size_t)NPOS * 128 * 2;
    unsigned short* Vbf = (unsigned short*)ws;  ws += (size_t)NPOS * 128 * 2;

    // 1. hi/lo expansion of x (A-side), qkv_w/proj_w (B-side)
    prep_kernel<<<784, 256, 0, stream>>>(x, qkv_w, proj_w, Axq, Bxq, Bxp);

    // 2. QKV GEMM (streaming, LDS-free) -> Qf (fp32), Kbf, Vbf (bf16)
    {
        dim3 grid(384 / 64, NPOS / 64);
        gemm_stream_kernel<1><<<grid, 256, 0, stream>>>(
            Axq, Bxq, qkv_b, nullptr, 0, Qf, Kbf, Vbf);
    }
    // 3. fused neighborhood attention -> Ap (bf16 hi|lo|hi)
    {
        dim3 grid(72, NHEADS);
        attn_kernel<<<grid, 640, 0, stream>>>(Qf, Kbf, Vbf, Ap);
    }
    // 4. proj GEMM (streaming, LDS-free): -> out fp32
    {
        dim3 grid(DIMC / 64, NPOS / 64);
        gemm_stream_kernel<0><<<grid, 256, 0, stream>>>(
            Ap, Bxp, proj_b, out, DIMC, nullptr, nullptr, nullptr);
    }
}

// Round 10
// 99.847 us; speedup vs baseline: 1.2441x; 1.2441x over previous
//
#include <hip/hip_runtime.h>
#include <hip/hip_bf16.h>
#include <cstddef>

// Problem constants
#define DIMC   128
#define NHEADS 8
#define HDIM   16
#define DD     5
#define HH     24
#define WW_    48
#define NPOS   (DD * HH * WW_)     // 5760
#define SCALE  0.25f

typedef short  bf16x8 __attribute__((ext_vector_type(8)));
typedef float  f32x4  __attribute__((ext_vector_type(4)));

__device__ __forceinline__ unsigned short f2bf(float f) {
    unsigned u = __float_as_uint(f);
    u = (u + 0x7FFFu + ((u >> 16) & 1u)) >> 16;   // RNE
    return (unsigned short)u;
}
__device__ __forceinline__ float bf2f(unsigned short s) {
    return __uint_as_float(((unsigned)s) << 16);
}

// ---------------------------------------------------------------------------
// QKV GEMM with fused fp32->bf16 hi/lo conversion (no prep kernel).
// C[M][384] = x[M][128] @ qkv_w[384][128]^T + b as 3-term bf16 split:
// hi*hi + lo*hi + hi*lo (missing lo*lo ~2^-18).
// B-tile converted into LDS as [hi(128)|lo(128)]; A (x) fragments converted
// in registers per k-group. Grid (6, 90) = 540 blocks, 256 thr.
// Epilogue: Q as bf16 hi/lo pairs (Qhl[pos][h*32+{hi16|lo16}]), K/V bf16.
// ---------------------------------------------------------------------------
__global__ __launch_bounds__(256, 3) void gemm_qkv_kernel(
    const float* __restrict__ x,
    const float* __restrict__ wq,
    const float* __restrict__ qkv_b,
    unsigned short* __restrict__ Qhl,
    unsigned short* __restrict__ Kbf,
    unsigned short* __restrict__ Vbf)
{
    __shared__ __align__(16) unsigned short Bs[64][264];  // [hi128|lo128|pad8]

    const int tid = threadIdx.x;
    const int bn  = blockIdx.x * 64;
    const int bm  = blockIdx.y * 64;

    for (int i = tid; i < 2048; i += 256) {
        const int r = i >> 5, c4 = (i & 31) * 4;
        const float4 v = *(const float4*)(wq + (size_t)(bn + r) * 128 + c4);
        ushort4 hi, lo;
        hi.x = f2bf(v.x); hi.y = f2bf(v.y); hi.z = f2bf(v.z); hi.w = f2bf(v.w);
        lo.x = f2bf(v.x - bf2f(hi.x));
        lo.y = f2bf(v.y - bf2f(hi.y));
        lo.z = f2bf(v.z - bf2f(hi.z));
        lo.w = f2bf(v.w - bf2f(hi.w));
        *(ushort4*)(&Bs[r][c4])       = hi;
        *(ushort4*)(&Bs[r][128 + c4]) = lo;
    }
    __syncthreads();

    const int w    = tid >> 6;
    const int lane = tid & 63;
    const int ln   = lane & 15;
    const int quad = lane >> 4;
    const int row  = bm + w * 16 + ln;
    const float* ar = x + (size_t)row * 128 + quad * 8;

    f32x4 acc[4] = {};
    #pragma unroll
    for (int kcg = 0; kcg < 4; ++kcg) {
        const float4 xa = *(const float4*)(ar + kcg * 32);
        const float4 xb = *(const float4*)(ar + kcg * 32 + 4);
        bf16x8 ahi, alo;
        {
            const float vv[8] = {xa.x, xa.y, xa.z, xa.w, xb.x, xb.y, xb.z, xb.w};
            #pragma unroll
            for (int j = 0; j < 8; ++j) {
                const unsigned short hh = f2bf(vv[j]);
                ahi[j] = (short)hh;
                alo[j] = (short)f2bf(vv[j] - bf2f(hh));
            }
        }
        #pragma unroll
        for (int nt = 0; nt < 4; ++nt) {
            const bf16x8 bhi = *(const bf16x8*)(&Bs[nt * 16 + ln][kcg * 32 + quad * 8]);
            const bf16x8 blo = *(const bf16x8*)(&Bs[nt * 16 + ln][128 + kcg * 32 + quad * 8]);
            acc[nt] = __builtin_amdgcn_mfma_f32_16x16x32_bf16(ahi, bhi, acc[nt], 0, 0, 0);
            acc[nt] = __builtin_amdgcn_mfma_f32_16x16x32_bf16(alo, bhi, acc[nt], 0, 0, 0);
            acc[nt] = __builtin_amdgcn_mfma_f32_16x16x32_bf16(ahi, blo, acc[nt], 0, 0, 0);
        }
    }

    #pragma unroll
    for (int nt = 0; nt < 4; ++nt) {
        const int col = bn + nt * 16 + ln;
        const float bv = qkv_b[col];
        #pragma unroll
        for (int r = 0; r < 4; ++r) {
            const int orow = bm + w * 16 + quad * 4 + r;
            const float val = acc[nt][r] + bv;
            if (col < 128) {               // q -> hi/lo pair
                const int h = col >> 4, ci = col & 15;
                const unsigned short hi = f2bf(val);
                Qhl[(size_t)orow * 256 + h * 32 + ci]      = hi;
                Qhl[(size_t)orow * 256 + h * 32 + 16 + ci] = f2bf(val - bf2f(hi));
            } else if (col < 256) {        // k -> bf16
                Kbf[(size_t)orow * 128 + (col - 128)] = f2bf(val);
            } else {                       // v -> bf16
                Vbf[(size_t)orow * 128 + (col - 256)] = f2bf(val);
            }
        }
    }
}

// ---------------------------------------------------------------------------
// Proj GEMM: out[M][128] = Ap(hi|lo)[M][256] @ proj_w[128][128]^T + b.
// A bf16 hi|lo (from attn); B converted fp32->hi|lo into LDS in-kernel.
// Grid (2, 180) = 360 blocks of 128 thr (32x64 tile) so all CUs get work.
// ---------------------------------------------------------------------------
__global__ __launch_bounds__(128, 2) void gemm_proj_kernel(
    const unsigned short* __restrict__ Ap,   // [5760][256] bf16 hi|lo
    const float* __restrict__ wp,
    const float* __restrict__ proj_b,
    float* __restrict__ out)
{
    __shared__ __align__(16) unsigned short Bs[64][264];  // [hi128|lo128|pad8]

    const int tid = threadIdx.x;
    const int bn  = blockIdx.x * 64;
    const int bm  = blockIdx.y * 32;

    for (int i = tid; i < 2048; i += 128) {
        const int r = i >> 5, c4 = (i & 31) * 4;
        const float4 v = *(const float4*)(wp + (size_t)(bn + r) * 128 + c4);
        ushort4 hi, lo;
        hi.x = f2bf(v.x); hi.y = f2bf(v.y); hi.z = f2bf(v.z); hi.w = f2bf(v.w);
        lo.x = f2bf(v.x - bf2f(hi.x));
        lo.y = f2bf(v.y - bf2f(hi.y));
        lo.z = f2bf(v.z - bf2f(hi.z));
        lo.w = f2bf(v.w - bf2f(hi.w));
        *(ushort4*)(&Bs[r][c4])       = hi;
        *(ushort4*)(&Bs[r][128 + c4]) = lo;
    }
    __syncthreads();

    const int w    = tid >> 6;   // 0..1
    const int lane = tid & 63;
    const int ln   = lane & 15;
    const int quad = lane >> 4;
    const int row  = bm + w * 16 + ln;
    const unsigned short* ar = Ap + (size_t)row * 256 + quad * 8;

    f32x4 acc[4] = {};
    #pragma unroll
    for (int kcg = 0; kcg < 4; ++kcg) {
        const bf16x8 ahi = *(const bf16x8*)(ar + kcg * 32);
        const bf16x8 alo = *(const bf16x8*)(ar + 128 + kcg * 32);
        #pragma unroll
        for (int nt = 0; nt < 4; ++nt) {
            const bf16x8 bhi = *(const bf16x8*)(&Bs[nt * 16 + ln][kcg * 32 + quad * 8]);
            const bf16x8 blo = *(const bf16x8*)(&Bs[nt * 16 + ln][128 + kcg * 32 + quad * 8]);
            acc[nt] = __builtin_amdgcn_mfma_f32_16x16x32_bf16(ahi, bhi, acc[nt], 0, 0, 0);
            acc[nt] = __builtin_amdgcn_mfma_f32_16x16x32_bf16(alo, bhi, acc[nt], 0, 0, 0);
            acc[nt] = __builtin_amdgcn_mfma_f32_16x16x32_bf16(ahi, blo, acc[nt], 0, 0, 0);
        }
    }

    #pragma unroll
    for (int nt = 0; nt < 4; ++nt) {
        const int col = bn + nt * 16 + ln;
        const float bv = proj_b[col];
        #pragma unroll
        for (int r = 0; r < 4; ++r) {
            const int orow = bm + w * 16 + quad * 4 + r;
            out[(size_t)orow * 128 + col] = acc[nt][r] + bv;
        }
    }
}

// ---------------------------------------------------------------------------
// Fused neighborhood attention — R5 structure verbatim (measured best).
// Changes vs R5: Ap epilogue writes [hi|lo] at stride 256 (third segment
// dropped — proj reuses the hi fragment), and nothing else.
// l-reduction: lanes (ln, quad) hold disjoint u-partials for query ln ->
// reduce ACROSS QUADS (shfl_xor 16, 32), store per-query red_l.
// (R9 bug: reduced across ln instead -> normalized by slab-total l.)
// ---------------------------------------------------------------------------
__global__ __launch_bounds__(256, 3) void attn_kernel(
    const unsigned short* __restrict__ Qhl,   // [5760][256] bf16 per-head hi|lo
    const unsigned short* __restrict__ Kbf,   // [5760][128] bf16
    const unsigned short* __restrict__ Vbf,   // [5760][128] bf16
    unsigned short* __restrict__ Ap)          // [5760][256] bf16 hi|lo
{
    __shared__ __align__(16) char smem[34560];
    unsigned short (*Vt)[520] = (unsigned short(*)[520])smem;          // 16640 B
    unsigned short (*Qb)[40]  = (unsigned short(*)[40])(smem + 16640); //  6400 B
    unsigned short* PwBase    = (unsigned short*)(smem + 23040);       // 10240 B
    float* red_l              = (float*)(smem + 33280);                //  1280 B
    float* redO               = (float*)smem;                          // 20480 B overlay

    const int tile = blockIdx.x;
    const int h    = blockIdx.y;
    const int ty0  = (tile / 12) * 4;
    const int tx0  = (tile % 12) * 4;
    const int tid  = threadIdx.x;

    // ---- stage V^T (bf16) ----
    for (int i = tid; i < 1024; i += 256) {
        const int u = i >> 1, half = i & 1;
        if (u < 500) {
            const int dp = u / 100;
            const int rr = u - dp * 100;
            const int yy = rr / 10;
            const int xx = rr - yy * 10;
            int y = ty0 - 3 + yy; if (y < 0) y += HH;  if (y >= HH) y -= HH;
            int x = tx0 - 3 + xx; if (x < 0) x += WW_; if (x >= WW_) x -= WW_;
            const int g = (dp * HH + y) * WW_ + x;
            const bf16x8 v = *(const bf16x8*)(Vbf + (size_t)g * 128 + h * 16 + half * 8);
            #pragma unroll
            for (int c = 0; c < 8; ++c) Vt[half * 8 + c][u] = (unsigned short)v[c];
        } else {
            #pragma unroll
            for (int c = 0; c < 8; ++c) Vt[half * 8 + c][u] = 0;
        }
    }
    // ---- stage Q tile (straight bf16 copy) ----
    for (int i = tid; i < 320; i += 256) {
        const int p = i >> 2, seg = i & 3;
        const int d = p >> 4, s = p & 15;
        const int sy = s >> 2, sx = s & 3;
        const int g = (d * HH + ty0 + sy) * WW_ + tx0 + sx;
        *(bf16x8*)(&Qb[p][seg * 8]) = *(const bf16x8*)(Qhl + (size_t)g * 256 + h * 32 + seg * 8);
    }
    __syncthreads();

    const int w    = tid >> 6;
    const int lane = tid & 63;
    const int ln   = lane & 15;
    const int quad = lane >> 4;
    const int sy   = ln >> 2, sx = ln & 3;

    unsigned short* Pw = PwBase + w * 1280;  // [2][16][40]

    bf16x8 qf[5];
    #pragma unroll
    for (int mt = 0; mt < 5; ++mt)
        qf[mt] = *(const bf16x8*)(&Qb[mt * 16 + ln][quad * 8]);

    f32x4 Ow[5] = {};
    float lsum[5] = {};

    for (int chunk = 0; chunk < 4; ++chunk) {
        const int u0 = (w * 4 + chunk) * 32;

        int rowa, rowb;
        {
            const int ua = u0 + ln      < 500 ? u0 + ln      : 499;
            const int ub = u0 + 16 + ln < 500 ? u0 + 16 + ln : 499;
            int dp = ua / 100, rr = ua - dp * 100, yy = rr / 10, xx = rr - yy * 10;
            int y = ty0 - 3 + yy; if (y < 0) y += HH;  if (y >= HH) y -= HH;
            int x = tx0 - 3 + xx; if (x < 0) x += WW_; if (x >= WW_) x -= WW_;
            rowa = (dp * HH + y) * WW_ + x;
            dp = ub / 100; rr = ub - dp * 100; yy = rr / 10; xx = rr - yy * 10;
            y = ty0 - 3 + yy; if (y < 0) y += HH;  if (y >= HH) y -= HH;
            x = tx0 - 3 + xx; if (x < 0) x += WW_; if (x >= WW_) x -= WW_;
            rowb = (dp * HH + y) * WW_ + x;
        }
        const bf16x8 ka = *(const bf16x8*)(Kbf + (size_t)rowa * 128 + h * 16 + (quad & 1) * 8);
        const bf16x8 kb = *(const bf16x8*)(Kbf + (size_t)rowb * 128 + h * 16 + (quad & 1) * 8);

        bool msk[2][4];
        #pragma unroll
        for (int b = 0; b < 2; ++b)
            #pragma unroll
            for (int r = 0; r < 4; ++r) {
                const int u = u0 + 16 * b + 4 * quad + r;
                const int rr = u % 100;
                const int uy = rr / 10, ux = rr - uy * 10;
                msk[b][r] = (u < 500) && ((unsigned)(uy - sy) <= 6u)
                                      && ((unsigned)(ux - sx) <= 6u);
            }

        const bf16x8 vf = *(const bf16x8*)(&Vt[ln][u0 + quad * 8]);

        #pragma unroll
        for (int mt = 0; mt < 5; ++mt) {
            f32x4 s0 = __builtin_amdgcn_mfma_f32_16x16x32_bf16(
                ka, qf[mt], (f32x4){0.f, 0.f, 0.f, 0.f}, 0, 0, 0);
            f32x4 s1 = __builtin_amdgcn_mfma_f32_16x16x32_bf16(
                kb, qf[mt], (f32x4){0.f, 0.f, 0.f, 0.f}, 0, 0, 0);

            unsigned short* pw = Pw + (mt & 1) * 640 + ln * 40;
            #pragma unroll
            for (int b = 0; b < 2; ++b) {
                const f32x4 s = b ? s1 : s0;
                unsigned short e[4];
                #pragma unroll
                for (int r = 0; r < 4; ++r) {
                    const float ev = msk[b][r] ? __expf(fmaf(s[r], SCALE, -8.0f)) : 0.f;
                    e[r] = f2bf(ev);
                    lsum[mt] += bf2f(e[r]);
                }
                *(unsigned*)(pw + 16 * b + 4 * quad)     = (unsigned)e[0] | ((unsigned)e[1] << 16);
                *(unsigned*)(pw + 16 * b + 4 * quad + 2) = (unsigned)e[2] | ((unsigned)e[3] << 16);
            }
            const bf16x8 pf = *(const bf16x8*)(Pw + (mt & 1) * 640 + ln * 40 + quad * 8);
            Ow[mt] = __builtin_amdgcn_mfma_f32_16x16x32_bf16(vf, pf, Ow[mt], 0, 0, 0);
        }
    }

    // ---- l: lanes (ln, quad) hold disjoint u-partials for query ln ->
    //      reduce ACROSS QUADS (xor 16, 32). All lanes then hold full sums.
    #pragma unroll
    for (int mt = 0; mt < 5; ++mt) {
        lsum[mt] += __shfl_xor(lsum[mt], 16);
        lsum[mt] += __shfl_xor(lsum[mt], 32);
    }

    __syncthreads();   // all Vt/Qb/Pw reads done; safe to overlay redO

    if (quad == 0) {
        #pragma unroll
        for (int mt = 0; mt < 5; ++mt)
            red_l[w * 80 + mt * 16 + ln] = lsum[mt];
    }
    #pragma unroll
    for (int mt = 0; mt < 5; ++mt)
        #pragma unroll
        for (int r = 0; r < 4; ++r)
            redO[(size_t)((w * 5 + mt) * 16 + quad * 4 + r) * 16 + ln] = Ow[mt][r];
    __syncthreads();

    // ---- final: sum 4 wave-partials, normalize, write Ap [hi|lo] ----
    for (int i = tid; i < 1280; i += 256) {
        const int m = i >> 4, c = i & 15;     // m: query 0..79, c: channel
        const int mt = m >> 4, mloc = m & 15;
        float o = 0.f, l = 0.f;
        #pragma unroll
        for (int w4 = 0; w4 < 4; ++w4) {
            o += redO[(size_t)((w4 * 5 + mt) * 16 + c) * 16 + mloc];
            l += red_l[w4 * 80 + m];
        }
        const float val = o / l;
        const int qsy = (mloc >> 2), qsx = mloc & 3;
        const size_t g = (size_t)((mt * HH + ty0 + qsy) * WW_ + (tx0 + qsx));
        const unsigned short hi = f2bf(val);
        const unsigned short lo = f2bf(val - bf2f(hi));
        unsigned short* row = Ap + g * 256 + h * HDIM + c;
        row[0]   = hi;
        row[128] = lo;
    }
}

// ---------------------------------------------------------------------------
extern "C" void kernel_launch(void* const* d_in, const int* in_sizes, int n_in,
                              void* d_out, int out_size, void* d_ws, size_t ws_size,
                              hipStream_t stream)
{
    const float* x      = (const float*)d_in[0];
    const float* qkv_w  = (const float*)d_in[1];
    const float* qkv_b  = (const float*)d_in[2];
    const float* proj_w = (const float*)d_in[3];
    const float* proj_b = (const float*)d_in[4];
    float* out = (float*)d_out;

    char* ws = (char*)d_ws;
    unsigned short* Ap  = (unsigned short*)ws;  ws += (size_t)NPOS * 256 * 2;  // attn out hi|lo
    unsigned short* Qhl = (unsigned short*)ws;  ws += (size_t)NPOS * 256 * 2;  // q hi|lo per head
    unsigned short* Kbf = (unsigned short*)ws;  ws += (size_t)NPOS * 128 * 2;
    unsigned short* Vbf = (unsigned short*)ws;  ws += (size_t)NPOS * 128 * 2;

    // 1. QKV GEMM (fused fp32->hi/lo conversion) -> Qhl, Kbf, Vbf
    {
        dim3 grid(384 / 64, NPOS / 64);
        gemm_qkv_kernel<<<grid, 256, 0, stream>>>(x, qkv_w, qkv_b, Qhl, Kbf, Vbf);
    }
    // 2. fused neighborhood attention -> Ap (bf16 hi|lo)
    {
        dim3 grid(72, NHEADS);
        attn_kernel<<<grid, 256, 0, stream>>>(Qhl, Kbf, Vbf, Ap);
    }
    // 3. proj GEMM (fused B conversion) -> out fp32
    {
        dim3 grid(DIMC / 64, NPOS / 32);
        gemm_proj_kernel<<<grid, 128, 0, stream>>>(Ap, proj_w, proj_b, out);
    }
}

// Round 11
// 99.132 us; speedup vs baseline: 1.2530x; 1.0072x over previous
//
#include <hip/hip_runtime.h>
#include <hip/hip_bf16.h>
#include <cstddef>

// Problem constants
#define DIMC   128
#define NHEADS 8
#define HDIM   16
#define DD     5
#define HH     24
#define WW_    48
#define NPOS   (DD * HH * WW_)     // 5760
#define SCALE  0.25f

typedef short  bf16x8 __attribute__((ext_vector_type(8)));
typedef float  f32x4  __attribute__((ext_vector_type(4)));

__device__ __forceinline__ unsigned short f2bf(float f) {
    unsigned u = __float_as_uint(f);
    u = (u + 0x7FFFu + ((u >> 16) & 1u)) >> 16;   // RNE
    return (unsigned short)u;
}
__device__ __forceinline__ float bf2f(unsigned short s) {
    return __uint_as_float(((unsigned)s) << 16);
}

// ---------------------------------------------------------------------------
// QKV GEMM with fused fp32->bf16 hi/lo conversion (unchanged from R10).
// C[M][384] = x[M][128] @ qkv_w[384][128]^T + b as 3-term bf16 split.
// ---------------------------------------------------------------------------
__global__ __launch_bounds__(256, 3) void gemm_qkv_kernel(
    const float* __restrict__ x,
    const float* __restrict__ wq,
    const float* __restrict__ qkv_b,
    unsigned short* __restrict__ Qhl,
    unsigned short* __restrict__ Kbf,
    unsigned short* __restrict__ Vbf)
{
    __shared__ __align__(16) unsigned short Bs[64][264];  // [hi128|lo128|pad8]

    const int tid = threadIdx.x;
    const int bn  = blockIdx.x * 64;
    const int bm  = blockIdx.y * 64;

    for (int i = tid; i < 2048; i += 256) {
        const int r = i >> 5, c4 = (i & 31) * 4;
        const float4 v = *(const float4*)(wq + (size_t)(bn + r) * 128 + c4);
        ushort4 hi, lo;
        hi.x = f2bf(v.x); hi.y = f2bf(v.y); hi.z = f2bf(v.z); hi.w = f2bf(v.w);
        lo.x = f2bf(v.x - bf2f(hi.x));
        lo.y = f2bf(v.y - bf2f(hi.y));
        lo.z = f2bf(v.z - bf2f(hi.z));
        lo.w = f2bf(v.w - bf2f(hi.w));
        *(ushort4*)(&Bs[r][c4])       = hi;
        *(ushort4*)(&Bs[r][128 + c4]) = lo;
    }
    __syncthreads();

    const int w    = tid >> 6;
    const int lane = tid & 63;
    const int ln   = lane & 15;
    const int quad = lane >> 4;
    const int row  = bm + w * 16 + ln;
    const float* ar = x + (size_t)row * 128 + quad * 8;

    f32x4 acc[4] = {};
    #pragma unroll
    for (int kcg = 0; kcg < 4; ++kcg) {
        const float4 xa = *(const float4*)(ar + kcg * 32);
        const float4 xb = *(const float4*)(ar + kcg * 32 + 4);
        bf16x8 ahi, alo;
        {
            const float vv[8] = {xa.x, xa.y, xa.z, xa.w, xb.x, xb.y, xb.z, xb.w};
            #pragma unroll
            for (int j = 0; j < 8; ++j) {
                const unsigned short hh = f2bf(vv[j]);
                ahi[j] = (short)hh;
                alo[j] = (short)f2bf(vv[j] - bf2f(hh));
            }
        }
        #pragma unroll
        for (int nt = 0; nt < 4; ++nt) {
            const bf16x8 bhi = *(const bf16x8*)(&Bs[nt * 16 + ln][kcg * 32 + quad * 8]);
            const bf16x8 blo = *(const bf16x8*)(&Bs[nt * 16 + ln][128 + kcg * 32 + quad * 8]);
            acc[nt] = __builtin_amdgcn_mfma_f32_16x16x32_bf16(ahi, bhi, acc[nt], 0, 0, 0);
            acc[nt] = __builtin_amdgcn_mfma_f32_16x16x32_bf16(alo, bhi, acc[nt], 0, 0, 0);
            acc[nt] = __builtin_amdgcn_mfma_f32_16x16x32_bf16(ahi, blo, acc[nt], 0, 0, 0);
        }
    }

    #pragma unroll
    for (int nt = 0; nt < 4; ++nt) {
        const int col = bn + nt * 16 + ln;
        const float bv = qkv_b[col];
        #pragma unroll
        for (int r = 0; r < 4; ++r) {
            const int orow = bm + w * 16 + quad * 4 + r;
            const float val = acc[nt][r] + bv;
            if (col < 128) {               // q -> hi/lo pair
                const int h = col >> 4, ci = col & 15;
                const unsigned short hi = f2bf(val);
                Qhl[(size_t)orow * 256 + h * 32 + ci]      = hi;
                Qhl[(size_t)orow * 256 + h * 32 + 16 + ci] = f2bf(val - bf2f(hi));
            } else if (col < 256) {        // k -> bf16
                Kbf[(size_t)orow * 128 + (col - 128)] = f2bf(val);
            } else {                       // v -> bf16
                Vbf[(size_t)orow * 128 + (col - 256)] = f2bf(val);
            }
        }
    }
}

// ---------------------------------------------------------------------------
// Proj GEMM v2: out = ((O0+O1) * 1/(l0+l1)) @ proj_w^T + b.
// A built in-registers from attn's fp32 partials (combine + normalize +
// hi/lo split); B converted fp32->hi|lo into LDS. Per kcg the 8 fragment
// channels lie in ONE head: h = kcg*2 + (quad>>1) -> one scalar inv each.
// Grid (2, 180) = 360 blocks of 128 thr.
// ---------------------------------------------------------------------------
__global__ __launch_bounds__(128, 2) void gemm_proj_kernel(
    const float* __restrict__ Opart,   // [2][5760][128] fp32 unnormalized
    const float* __restrict__ Lpart,   // [2][5760][8]   fp32 row-sums
    const float* __restrict__ wp,
    const float* __restrict__ proj_b,
    float* __restrict__ out)
{
    __shared__ __align__(16) unsigned short Bs[64][264];  // [hi128|lo128|pad8]

    const int tid = threadIdx.x;
    const int bn  = blockIdx.x * 64;
    const int bm  = blockIdx.y * 32;

    for (int i = tid; i < 2048; i += 128) {
        const int r = i >> 5, c4 = (i & 31) * 4;
        const float4 v = *(const float4*)(wp + (size_t)(bn + r) * 128 + c4);
        ushort4 hi, lo;
        hi.x = f2bf(v.x); hi.y = f2bf(v.y); hi.z = f2bf(v.z); hi.w = f2bf(v.w);
        lo.x = f2bf(v.x - bf2f(hi.x));
        lo.y = f2bf(v.y - bf2f(hi.y));
        lo.z = f2bf(v.z - bf2f(hi.z));
        lo.w = f2bf(v.w - bf2f(hi.w));
        *(ushort4*)(&Bs[r][c4])       = hi;
        *(ushort4*)(&Bs[r][128 + c4]) = lo;
    }
    __syncthreads();

    const int w    = tid >> 6;   // 0..1
    const int lane = tid & 63;
    const int ln   = lane & 15;
    const int quad = lane >> 4;
    const int row  = bm + w * 16 + ln;

    // per-row inverse softmax denominators (8 heads, two halves)
    float linv[8];
    {
        const float4 l0a = *(const float4*)(Lpart + (size_t)row * 8);
        const float4 l0b = *(const float4*)(Lpart + (size_t)row * 8 + 4);
        const float4 l1a = *(const float4*)(Lpart + (size_t)(NPOS + row) * 8);
        const float4 l1b = *(const float4*)(Lpart + (size_t)(NPOS + row) * 8 + 4);
        linv[0] = 1.0f / (l0a.x + l1a.x); linv[1] = 1.0f / (l0a.y + l1a.y);
        linv[2] = 1.0f / (l0a.z + l1a.z); linv[3] = 1.0f / (l0a.w + l1a.w);
        linv[4] = 1.0f / (l0b.x + l1b.x); linv[5] = 1.0f / (l0b.y + l1b.y);
        linv[6] = 1.0f / (l0b.z + l1b.z); linv[7] = 1.0f / (l0b.w + l1b.w);
    }
    const float* o0 = Opart + (size_t)row * 128 + quad * 8;
    const float* o1 = o0 + (size_t)NPOS * 128;

    f32x4 acc[4] = {};
    #pragma unroll
    for (int kcg = 0; kcg < 4; ++kcg) {
        const float4 a0 = *(const float4*)(o0 + kcg * 32);
        const float4 a0b = *(const float4*)(o0 + kcg * 32 + 4);
        const float4 a1 = *(const float4*)(o1 + kcg * 32);
        const float4 a1b = *(const float4*)(o1 + kcg * 32 + 4);
        const float inv = linv[kcg * 2 + (quad >> 1)];
        const float vv[8] = {
            (a0.x + a1.x) * inv, (a0.y + a1.y) * inv,
            (a0.z + a1.z) * inv, (a0.w + a1.w) * inv,
            (a0b.x + a1b.x) * inv, (a0b.y + a1b.y) * inv,
            (a0b.z + a1b.z) * inv, (a0b.w + a1b.w) * inv };
        bf16x8 ahi, alo;
        #pragma unroll
        for (int j = 0; j < 8; ++j) {
            const unsigned short hh = f2bf(vv[j]);
            ahi[j] = (short)hh;
            alo[j] = (short)f2bf(vv[j] - bf2f(hh));
        }
        #pragma unroll
        for (int nt = 0; nt < 4; ++nt) {
            const bf16x8 bhi = *(const bf16x8*)(&Bs[nt * 16 + ln][kcg * 32 + quad * 8]);
            const bf16x8 blo = *(const bf16x8*)(&Bs[nt * 16 + ln][128 + kcg * 32 + quad * 8]);
            acc[nt] = __builtin_amdgcn_mfma_f32_16x16x32_bf16(ahi, bhi, acc[nt], 0, 0, 0);
            acc[nt] = __builtin_amdgcn_mfma_f32_16x16x32_bf16(alo, bhi, acc[nt], 0, 0, 0);
            acc[nt] = __builtin_amdgcn_mfma_f32_16x16x32_bf16(ahi, blo, acc[nt], 0, 0, 0);
        }
    }

    #pragma unroll
    for (int nt = 0; nt < 4; ++nt) {
        const int col = bn + nt * 16 + ln;
        const float bv = proj_b[col];
        #pragma unroll
        for (int r = 0; r < 4; ++r) {
            const int orow = bm + w * 16 + quad * 4 + r;
            out[(size_t)orow * 128 + col] = acc[nt][r] + bv;
        }
    }
}

// ---------------------------------------------------------------------------
// Fused neighborhood attention v3: u-range split across 2 blocks.
// Grid (144, 8): tile = bx>>1, half = bx&1. Block covers u in
// [half*256, half*256+256); 4 waves x 2 chunks of 32 each (R10 inner loop
// verbatim otherwise). Output: UNNORMALIZED fp32 O partials + l row-sums;
// the proj kernel combines halves and normalizes. 1152 blocks = 4.5/CU
// (2x R10's parallelism); LDS 26.4 KB.
// ---------------------------------------------------------------------------
__global__ __launch_bounds__(256, 4) void attn_kernel(
    const unsigned short* __restrict__ Qhl,   // [5760][256] bf16 per-head hi|lo
    const unsigned short* __restrict__ Kbf,   // [5760][128] bf16
    const unsigned short* __restrict__ Vbf,   // [5760][128] bf16
    float* __restrict__ Opart,                // [2][5760][128] fp32
    float* __restrict__ Lpart)                // [2][5760][8]   fp32
{
    // LDS layout:
    //   Vt   : ushort[16][264]  @     0   (8448 B)  V^T for this u-half
    //   Qb   : ushort[80][40]   @  8448   (6400 B)
    //   Pw   : ushort[4][2][16][40] @ 14848 (10240 B)
    //   red_l: float[4][80]     @ 25088   (1280 B)
    //   redO : float[4*5*16][16] @ 0      (20480 B) overlay post-barrier
    __shared__ __align__(16) char smem[26368];
    unsigned short (*Vt)[264] = (unsigned short(*)[264])smem;
    unsigned short (*Qb)[40]  = (unsigned short(*)[40])(smem + 8448);
    unsigned short* PwBase    = (unsigned short*)(smem + 14848);
    float* red_l              = (float*)(smem + 25088);
    float* redO               = (float*)smem;

    const int bx   = blockIdx.x;
    const int tile = bx >> 1;
    const int half = bx & 1;
    const int h    = blockIdx.y;
    const int ty0  = (tile / 12) * 4;
    const int tx0  = (tile % 12) * 4;
    const int tid  = threadIdx.x;

    // ---- stage V^T for this half's 256 u ----
    for (int i = tid; i < 512; i += 256) {
        const int ul = i >> 1, hf8 = i & 1;
        const int u  = half * 256 + ul;
        if (u < 500) {
            const int dp = u / 100;
            const int rr = u - dp * 100;
            const int yy = rr / 10;
            const int xx = rr - yy * 10;
            int y = ty0 - 3 + yy; if (y < 0) y += HH;  if (y >= HH) y -= HH;
            int x = tx0 - 3 + xx; if (x < 0) x += WW_; if (x >= WW_) x -= WW_;
            const int g = (dp * HH + y) * WW_ + x;
            const bf16x8 v = *(const bf16x8*)(Vbf + (size_t)g * 128 + h * 16 + hf8 * 8);
            #pragma unroll
            for (int c = 0; c < 8; ++c) Vt[hf8 * 8 + c][ul] = (unsigned short)v[c];
        } else {
            #pragma unroll
            for (int c = 0; c < 8; ++c) Vt[hf8 * 8 + c][ul] = 0;
        }
    }
    // ---- stage Q tile (straight bf16 copy) ----
    for (int i = tid; i < 320; i += 256) {
        const int p = i >> 2, seg = i & 3;
        const int d = p >> 4, s = p & 15;
        const int sy = s >> 2, sx = s & 3;
        const int g = (d * HH + ty0 + sy) * WW_ + tx0 + sx;
        *(bf16x8*)(&Qb[p][seg * 8]) = *(const bf16x8*)(Qhl + (size_t)g * 256 + h * 32 + seg * 8);
    }
    __syncthreads();

    const int w    = tid >> 6;
    const int lane = tid & 63;
    const int ln   = lane & 15;
    const int quad = lane >> 4;
    const int sy   = ln >> 2, sx = ln & 3;

    unsigned short* Pw = PwBase + w * 1280;  // [2][16][40]

    bf16x8 qf[5];
    #pragma unroll
    for (int mt = 0; mt < 5; ++mt)
        qf[mt] = *(const bf16x8*)(&Qb[mt * 16 + ln][quad * 8]);

    f32x4 Ow[5] = {};
    float lsum[5] = {};

    #pragma unroll
    for (int chunk = 0; chunk < 2; ++chunk) {
        const int u0g = (half * 8 + w * 2 + chunk) * 32;   // global u base
        const int u0l = (w * 2 + chunk) * 32;              // LDS-local u base

        int rowa, rowb;
        {
            const int ua = u0g + ln      < 500 ? u0g + ln      : 499;
            const int ub = u0g + 16 + ln < 500 ? u0g + 16 + ln : 499;
            int dp = ua / 100, rr = ua - dp * 100, yy = rr / 10, xx = rr - yy * 10;
            int y = ty0 - 3 + yy; if (y < 0) y += HH;  if (y >= HH) y -= HH;
            int x = tx0 - 3 + xx; if (x < 0) x += WW_; if (x >= WW_) x -= WW_;
            rowa = (dp * HH + y) * WW_ + x;
            dp = ub / 100; rr = ub - dp * 100; yy = rr / 10; xx = rr - yy * 10;
            y = ty0 - 3 + yy; if (y < 0) y += HH;  if (y >= HH) y -= HH;
            x = tx0 - 3 + xx; if (x < 0) x += WW_; if (x >= WW_) x -= WW_;
            rowb = (dp * HH + y) * WW_ + x;
        }
        const bf16x8 ka = *(const bf16x8*)(Kbf + (size_t)rowa * 128 + h * 16 + (quad & 1) * 8);
        const bf16x8 kb = *(const bf16x8*)(Kbf + (size_t)rowb * 128 + h * 16 + (quad & 1) * 8);

        bool msk[2][4];
        #pragma unroll
        for (int b = 0; b < 2; ++b)
            #pragma unroll
            for (int r = 0; r < 4; ++r) {
                const int u = u0g + 16 * b + 4 * quad + r;
                const int rr = u % 100;
                const int uy = rr / 10, ux = rr - uy * 10;
                msk[b][r] = (u < 500) && ((unsigned)(uy - sy) <= 6u)
                                      && ((unsigned)(ux - sx) <= 6u);
            }

        const bf16x8 vf = *(const bf16x8*)(&Vt[ln][u0l + quad * 8]);

        #pragma unroll
        for (int mt = 0; mt < 5; ++mt) {
            f32x4 s0 = __builtin_amdgcn_mfma_f32_16x16x32_bf16(
                ka, qf[mt], (f32x4){0.f, 0.f, 0.f, 0.f}, 0, 0, 0);
            f32x4 s1 = __builtin_amdgcn_mfma_f32_16x16x32_bf16(
                kb, qf[mt], (f32x4){0.f, 0.f, 0.f, 0.f}, 0, 0, 0);

            unsigned short* pw = Pw + (mt & 1) * 640 + ln * 40;
            #pragma unroll
            for (int b = 0; b < 2; ++b) {
                const f32x4 s = b ? s1 : s0;
                unsigned short e[4];
                #pragma unroll
                for (int r = 0; r < 4; ++r) {
                    const float ev = msk[b][r] ? __expf(fmaf(s[r], SCALE, -8.0f)) : 0.f;
                    e[r] = f2bf(ev);
                    lsum[mt] += bf2f(e[r]);
                }
                *(unsigned*)(pw + 16 * b + 4 * quad)     = (unsigned)e[0] | ((unsigned)e[1] << 16);
                *(unsigned*)(pw + 16 * b + 4 * quad + 2) = (unsigned)e[2] | ((unsigned)e[3] << 16);
            }
            const bf16x8 pf = *(const bf16x8*)(Pw + (mt & 1) * 640 + ln * 40 + quad * 8);
            Ow[mt] = __builtin_amdgcn_mfma_f32_16x16x32_bf16(vf, pf, Ow[mt], 0, 0, 0);
        }
    }

    // ---- l: lanes (ln, quad) hold disjoint u-partials for query ln ->
    //      reduce ACROSS QUADS (xor 16, 32).
    #pragma unroll
    for (int mt = 0; mt < 5; ++mt) {
        lsum[mt] += __shfl_xor(lsum[mt], 16);
        lsum[mt] += __shfl_xor(lsum[mt], 32);
    }

    __syncthreads();   // all Vt/Qb/Pw reads done; safe to overlay redO

    if (quad == 0) {
        #pragma unroll
        for (int mt = 0; mt < 5; ++mt)
            red_l[w * 80 + mt * 16 + ln] = lsum[mt];
    }
    #pragma unroll
    for (int mt = 0; mt < 5; ++mt)
        #pragma unroll
        for (int r = 0; r < 4; ++r)
            redO[(size_t)((w * 5 + mt) * 16 + quad * 4 + r) * 16 + ln] = Ow[mt][r];
    __syncthreads();

    // ---- final: sum 4 wave-partials, write fp32 partials (no division) ----
    for (int i = tid; i < 1280; i += 256) {
        const int m = i >> 4, c = i & 15;     // m: query 0..79, c: channel
        const int mt = m >> 4, mloc = m & 15;
        float o = 0.f, l = 0.f;
        #pragma unroll
        for (int w4 = 0; w4 < 4; ++w4) {
            o += redO[(size_t)((w4 * 5 + mt) * 16 + c) * 16 + mloc];
            l += red_l[w4 * 80 + m];
        }
        const int qsy = (mloc >> 2), qsx = mloc & 3;
        const size_t g = (size_t)((mt * HH + ty0 + qsy) * WW_ + (tx0 + qsx));
        Opart[((size_t)half * NPOS + g) * 128 + h * HDIM + c] = o;
        if (c == 0) Lpart[((size_t)half * NPOS + g) * 8 + h] = l;
    }
}

// ---------------------------------------------------------------------------
extern "C" void kernel_launch(void* const* d_in, const int* in_sizes, int n_in,
                              void* d_out, int out_size, void* d_ws, size_t ws_size,
                              hipStream_t stream)
{
    const float* x      = (const float*)d_in[0];
    const float* qkv_w  = (const float*)d_in[1];
    const float* qkv_b  = (const float*)d_in[2];
    const float* proj_w = (const float*)d_in[3];
    const float* proj_b = (const float*)d_in[4];
    float* out = (float*)d_out;

    char* ws = (char*)d_ws;
    unsigned short* Qhl   = (unsigned short*)ws;  ws += (size_t)NPOS * 256 * 2;      // q hi|lo per head
    unsigned short* Kbf   = (unsigned short*)ws;  ws += (size_t)NPOS * 128 * 2;
    unsigned short* Vbf   = (unsigned short*)ws;  ws += (size_t)NPOS * 128 * 2;
    float*          Opart = (float*)ws;           ws += (size_t)2 * NPOS * 128 * 4;  // fp32 O partials
    float*          Lpart = (float*)ws;           ws += (size_t)2 * NPOS * 8 * 4;    // fp32 l partials

    // 1. QKV GEMM (fused fp32->hi/lo conversion) -> Qhl, Kbf, Vbf
    {
        dim3 grid(384 / 64, NPOS / 64);
        gemm_qkv_kernel<<<grid, 256, 0, stream>>>(x, qkv_w, qkv_b, Qhl, Kbf, Vbf);
    }
    // 2. fused neighborhood attention (u-split, 1152 blocks) -> Opart/Lpart
    {
        dim3 grid(144, NHEADS);
        attn_kernel<<<grid, 256, 0, stream>>>(Qhl, Kbf, Vbf, Opart, Lpart);
    }
    // 3. proj GEMM (combine halves + normalize + GEMM) -> out fp32
    {
        dim3 grid(DIMC / 64, NPOS / 32);
        gemm_proj_kernel<<<grid, 128, 0, stream>>>(Opart, Lpart, proj_w, proj_b, out);
    }
}